// Round 14
// baseline (150.121 us; speedup 1.0000x reference)
//
#include <hip/hip_runtime.h>
#include <hip/hip_bf16.h>

// B=32, N=207, T=24, E=128, H=8, d=16, DM=64, M=32
#define Bn 32
#define Nn 207
#define Tt 24
#define Ee 128
#define Hh 8
#define Dm 64
#define Mm 32
#define NBN (Bn * Nn)                // 6624
#define PT ((size_t)Nn * 16384)     // per-tensor Pt fragment elems

typedef __attribute__((ext_vector_type(8))) short bf16x8;
typedef __attribute__((ext_vector_type(4))) float f32x4;

// Compiler-only memory fence: zero instructions, forbids reordering of memory
// accesses across it. The arena overlays alias through DIFFERENT pointer types
// (bf16x8* reads vs unsigned short*/uint2* writes of the same LDS bytes); TBAA
// may declare those no-alias, licensing the scheduler to break the phase order
// (root cause of the R11/R12 out-corruption, ~5e-2 absmax).
#define MEMFENCE asm volatile("" ::: "memory")

__device__ __forceinline__ unsigned swz256(unsigned a) { return a ^ (((a >> 8) & 7u) << 4); }
// hardware packed f32->bf16 (RNE)
__device__ __forceinline__ unsigned cvtpk(float lo, float hi) {
  unsigned r;
  asm("v_cvt_pk_bf16_f32 %0, %1, %2" : "=v"(r) : "v"(lo), "v"(hi));
  return r;
}
__device__ __forceinline__ unsigned short f2bs(float f) {
  return (unsigned short)cvtpk(f, f);
}

// ---------------- builders (unchanged) ----------------
__global__ __launch_bounds__(256) void build_P_frag3(
    const float* __restrict__ qp1, const float* __restrict__ qp2,
    const float* __restrict__ kp1, const float* __restrict__ kp2,
    const float* __restrict__ vp1, const float* __restrict__ vp2,
    unsigned short* __restrict__ Pt) {
  const int tau = blockIdx.y;
  const float* p1 = (tau == 0) ? qp1 : (tau == 1) ? kp1 : vp1;
  const float* p2 = (tau == 0) ? qp2 : (tau == 1) ? kp2 : vp2;
  unsigned short* dst = Pt + (size_t)tau * PT;
  const int bid = blockIdx.x;
  const int n = bid >> 3;
  const int r8 = bid & 7;
  const int ks = r8 >> 1;
  const int chunk = ((r8 & 1) << 1) + (threadIdx.x >> 7);
  const int col = threadIdx.x & 127;
  const int base_i = ks * 32 + chunk * 8;
  const float* p1r = p1 + (size_t)(n * 64 + (base_i >> 1)) * Mm;
  const float* p2a = p2 + col;
  const float* p2b = p2 + 128 + col;
  float acc[8] = {};
#pragma unroll
  for (int m = 0; m < Mm; ++m) {
    float a = p2a[m * 256], b = p2b[m * 256];
#pragma unroll
    for (int jj = 0; jj < 4; ++jj) {
      float pv = p1r[jj * Mm + m];
      acc[2 * jj]     = fmaf(pv, a, acc[2 * jj]);
      acc[2 * jj + 1] = fmaf(pv, b, acc[2 * jj + 1]);
    }
  }
  const int nt = col >> 4;
  const int lane = (chunk << 4) | (col & 15);
  union { unsigned u[4]; uint4 v; } w;
#pragma unroll
  for (int jj = 0; jj < 4; ++jj) w.u[jj] = cvtpk(acc[2 * jj], acc[2 * jj + 1]);
  *(uint4*)(dst + (size_t)(((n * 8 + nt) * 4 + ks) * 64 + lane) * 8) = w.v;
}

__global__ __launch_bounds__(256) void build_W_frag(const float* __restrict__ W,
                                                    unsigned short* __restrict__ Wt) {
  for (int idx = threadIdx.x; idx < 1024; idx += 256) {
    int lane = idx & 63, ks = (idx >> 6) & 3, nt = idx >> 8;
    union { unsigned u[4]; uint4 v; } w;
#pragma unroll
    for (int jj = 0; jj < 4; ++jj) {
      float a = W[(size_t)(ks * 32 + (lane >> 4) * 8 + 2 * jj) * 64 + nt * 16 + (lane & 15)];
      float b = W[(size_t)(ks * 32 + (lane >> 4) * 8 + 2 * jj + 1) * 64 + nt * 16 + (lane & 15)];
      w.u[jj] = cvtpk(a, b);
    }
    *(uint4*)(Wt + (size_t)idx * 8) = w.v;
  }
}

struct P8 { unsigned u[8]; };

// One block per (b,n); 4 waves; 24576 B LDS -> 6 blocks/CU.
// R13 structure + MEMFENCE at every overlay phase boundary (fix for the
// R11/R12 schedule-sensitive corruption) + batched P0 staging loads (MLP).
// Arena(wv) = smem + wv*4608:
//   qs@0 [24][32] xor-swz (1536) | ks@1536 (1536) | inv@2304 [2][24] f32 (192)
//   vT@3072 [32][24] stride 48 (1536)
//   probs overlay @0 [2 hh][24 t][24 s] stride 48 (after all qs/ks frag reads)
// outh @18432 [24][128] bf16 swz256 (separate region).
__global__ __launch_bounds__(256, 6) void fused_attn(
    const float* __restrict__ Qin, const float* __restrict__ Kin,
    const float* __restrict__ Vin,
    const unsigned short* __restrict__ Ptq, const unsigned short* __restrict__ Ptk,
    const unsigned short* __restrict__ Ptv, const unsigned short* __restrict__ Wt,
    const float* __restrict__ bias,
    float* __restrict__ out, float* __restrict__ attn) {
  __shared__ __align__(16) char smem[24576];
  const int tid = threadIdx.x;
  const int lane = tid & 63;
  const int wv = tid >> 6;
  const int c = lane & 15;
  const int g = lane >> 4;
  const f32x4 zf = {0.f, 0.f, 0.f, 0.f};
  const bf16x8 zb = {0, 0, 0, 0, 0, 0, 0, 0};

  int bx = blockIdx.x;
  bx = (bx & 7) * 828 + (bx >> 3);          // bijective XCD swizzle (6624 = 8*828)
  const int n = bx >> 5;
  const int b = bx & 31;
  const size_t xbase = (size_t)(b * Nn + n) * (Tt * Ee);

  // ---- P0: stage xq/xk/xv. Batched: issue all 9 loads, then cvt+store ----
  {
    const float* src[3] = {Qin + xbase, Kin + xbase, Vin + xbase};
    float4 xr[9];
#pragma unroll
    for (int w = 0; w < 3; ++w)
#pragma unroll
      for (int it = 0; it < 3; ++it)
        xr[w * 3 + it] = *(const float4*)(src[w] + (size_t)(tid + 256 * it) * 4);
#pragma unroll
    for (int w = 0; w < 3; ++w)
#pragma unroll
      for (int it = 0; it < 3; ++it) {
        int e4 = tid + 256 * it;            // 768 float4 = 24x128
        unsigned a = swz256((unsigned)((e4 >> 5) * 256 + (e4 & 31) * 8));
        uint2 pk;
        pk.x = cvtpk(xr[w * 3 + it].x, xr[w * 3 + it].y);
        pk.y = cvtpk(xr[w * 3 + it].z, xr[w * 3 + it].w);
        *(uint2*)(smem + w * 6144 + a) = pk;
      }
  }
  __syncthreads();  // (1) staging ready

  // ---- P1: q/k/v proj; results packed bf16 in regs (8 uints each) ----
  P8 pq, pk_, pv_;
  {
#pragma unroll
    for (int w = 0; w < 3; ++w) {
      const unsigned short* Pf = (w == 0) ? Ptq : (w == 1) ? Ptk : Ptv;
      const char* xs = smem + w * 6144;
      f32x4 acc[2][2] = {{zf, zf}, {zf, zf}};
#pragma unroll
      for (int ks = 0; ks < 4; ++ks) {
        bf16x8 Bf[2], Af[2];
#pragma unroll
        for (int ntl = 0; ntl < 2; ++ntl)
          Bf[ntl] = *(const bf16x8*)(Pf + (size_t)(((n * 8 + (wv * 2 + ntl)) * 4 + ks) * 64 + lane) * 8);
#pragma unroll
        for (int mt = 0; mt < 2; ++mt) {
          int row = mt * 16 + c; row = row < 24 ? row : 23;
          Af[mt] = *(const bf16x8*)(xs + swz256((unsigned)(row * 256 + ks * 64 + g * 16)));
        }
        __builtin_amdgcn_s_setprio(1);
#pragma unroll
        for (int mt = 0; mt < 2; ++mt)
#pragma unroll
          for (int ntl = 0; ntl < 2; ++ntl)
            acc[mt][ntl] = __builtin_amdgcn_mfma_f32_16x16x32_bf16(Af[mt], Bf[ntl], acc[mt][ntl], 0, 0, 0);
        __builtin_amdgcn_s_setprio(0);
      }
      const float ps = (w == 0) ? 0.25f : 1.0f;   // fold softmax scale into q
      P8 r;
#pragma unroll
      for (int mt = 0; mt < 2; ++mt)
#pragma unroll
        for (int ntl = 0; ntl < 2; ++ntl)
#pragma unroll
          for (int half = 0; half < 2; ++half) {
            float a = fmaxf(acc[mt][ntl][half * 2], 0.f) * ps;
            float bb = fmaxf(acc[mt][ntl][half * 2 + 1], 0.f) * ps;
            r.u[(mt * 2 + ntl) * 2 + half] = cvtpk(a, bb);
          }
      if (w == 0) pq = r; else if (w == 1) pk_ = r; else pv_ = r;
    }
  }
  __syncthreads();  // (2) all staging reads done -> arenas live

  char* arena = smem + wv * 4608;

  // ---- P2a: unpack packed projections into arena slices ----
#pragma unroll
  for (int mt = 0; mt < 2; ++mt)
#pragma unroll
    for (int ntl = 0; ntl < 2; ++ntl)
#pragma unroll
      for (int half = 0; half < 2; ++half) {
        unsigned uq = pq.u[(mt * 2 + ntl) * 2 + half];
        unsigned uk = pk_.u[(mt * 2 + ntl) * 2 + half];
        unsigned uv = pv_.u[(mt * 2 + ntl) * 2 + half];
        int row0 = mt * 16 + g * 4 + half * 2;
        // vT: rows adjacent in [e][t] layout -> single uint store (both rows)
        if (row0 < 24)
          *(unsigned*)(arena + 3072 + (ntl * 16 + c) * 48 + row0 * 2) = uv;
#pragma unroll
        for (int rr = 0; rr < 2; ++rr) {
          int row = row0 + rr;
          if (row < 24) {
            unsigned short vq = (unsigned short)(rr ? (uq >> 16) : uq);
            unsigned short vk = (unsigned short)(rr ? (uk >> 16) : uk);
            unsigned adqk = (unsigned)(row * 64) +
                            (((unsigned)(ntl * 32 + c * 2)) ^ (((unsigned)row & 3u) << 4));
            *(unsigned short*)(arena + adqk) = vq;
            *(unsigned short*)(arena + 1536 + adqk) = vk;
          }
        }
      }
  MEMFENCE;  // P2a stores (ushort/uint) must complete-order before P2b reads (bf16x8)

  // ---- P2b: score fragments (all reads BEFORE probs overlay writes) ----
  bf16x8 Aq[2][2], Bk[2][2];   // [hh][mt/st]; k-dim = 16, g>=2 zero
#pragma unroll
  for (int hh = 0; hh < 2; ++hh)
#pragma unroll
    for (int mt = 0; mt < 2; ++mt) {
      int row = mt * 16 + c; row = row < 24 ? row : 23;
      unsigned ad = (unsigned)(row * 64) +
                    (((unsigned)(hh * 32 + g * 16)) ^ (((unsigned)row & 3u) << 4));
      Aq[hh][mt] = zb;
      Bk[hh][mt] = zb;
      if (g < 2) {
        Aq[hh][mt] = *(const bf16x8*)(arena + ad);
        Bk[hh][mt] = *(const bf16x8*)(arena + 1536 + ad);
      }
    }
  MEMFENCE;  // P2b qs/ks reads must order before P2c probs stores (overlay WAR)

  // ---- P2c: scores + exp; store UNNORMALIZED probs (no shuffles, no reduce) ----
#pragma unroll
  for (int hh = 0; hh < 2; ++hh) {
    f32x4 sc[2][2];
    __builtin_amdgcn_s_setprio(1);
#pragma unroll
    for (int mt = 0; mt < 2; ++mt)
#pragma unroll
      for (int st = 0; st < 2; ++st)
        sc[mt][st] = __builtin_amdgcn_mfma_f32_16x16x32_bf16(Aq[hh][mt], Bk[hh][st], zf, 0, 0, 0);
    __builtin_amdgcn_s_setprio(0);
#pragma unroll
    for (int mt = 0; mt < 2; ++mt)
#pragma unroll
      for (int r = 0; r < 4; ++r) {
        int t = mt * 16 + g * 4 + r;
        float e0 = (c <= t)      ? __expf(sc[mt][0][r]) : 0.f;   // bounded by e^9
        float e1 = (16 + c <= t) ? __expf(sc[mt][1][r]) : 0.f;
        if (t < 24) {
          unsigned u = cvtpk(e0, e1);
          *(unsigned short*)(arena + hh * 1152 + t * 48 + c * 2) = (unsigned short)u;
          if (c < 8)
            *(unsigned short*)(arena + hh * 1152 + t * 48 + (16 + c) * 2) = (unsigned short)(u >> 16);
        }
      }
  }
  MEMFENCE;  // P2c probs stores (ushort) must order before P2d reads (bf16x8/uint2 RAW)

  // ---- P2d: row-sum MFMA (B=ones) + PV; normalize in regs; attn; outh ----
  {
    bf16x8 Ap[2][2], Bv[2];
    const short one_bf = (short)0x3F80;
    bf16x8 onesf = {one_bf, one_bf, one_bf, one_bf, one_bf, one_bf, one_bf, one_bf};
    if (g >= 3) onesf = zb;   // k = g*8+j < 24 only
#pragma unroll
    for (int hh = 0; hh < 2; ++hh) {
      Bv[hh] = zb;
      if (g < 3) Bv[hh] = *(const bf16x8*)(arena + 3072 + (hh * 16 + c) * 48 + g * 16);
#pragma unroll
      for (int mt = 0; mt < 2; ++mt) {
        int row = mt * 16 + c; row = row < 24 ? row : 23;
        Ap[hh][mt] = zb;
        if (g < 3) Ap[hh][mt] = *(const bf16x8*)(arena + hh * 1152 + row * 48 + g * 16);
      }
    }
    f32x4 pv[2][2], su[2][2];
    __builtin_amdgcn_s_setprio(1);
#pragma unroll
    for (int hh = 0; hh < 2; ++hh)
#pragma unroll
      for (int mt = 0; mt < 2; ++mt) {
        su[hh][mt] = __builtin_amdgcn_mfma_f32_16x16x32_bf16(Ap[hh][mt], onesf, zf, 0, 0, 0);
        pv[hh][mt] = __builtin_amdgcn_mfma_f32_16x16x32_bf16(Ap[hh][mt], Bv[hh], zf, 0, 0, 0);
      }
    __builtin_amdgcn_s_setprio(0);
    MEMFENCE;  // Ap/Bv reads ordered before inv store (inv overlays ks bytes)
    // normalize pv rows; store inv (rows t = mt*16+g*4+r) for the attn write
#pragma unroll
    for (int hh = 0; hh < 2; ++hh)
#pragma unroll
      for (int mt = 0; mt < 2; ++mt) {
        float iv[4];
#pragma unroll
        for (int r = 0; r < 4; ++r) {
          iv[r] = __builtin_amdgcn_rcpf(su[hh][mt][r]);   // sum >= 1 for valid t
          pv[hh][mt][r] *= iv[r];
        }
        if (c == 0) {
#pragma unroll
          for (int rp = 0; rp < 4; rp += 2) {
            int t0 = mt * 16 + g * 4 + rp;
            if (t0 < 24) {
              float2 st2 = {iv[rp], iv[rp + 1]};
              *(float2*)(arena + 2304 + hh * 96 + t0 * 4) = st2;
            }
          }
        }
      }
    MEMFENCE;  // inv stores (float2) ordered before attn-path reads (uint2/float RAW)
    // attn global write: p_un * inv[t] (coalesced float4)
    const size_t abase = (size_t)(b * Nn + n) * (Hh * Tt * Tt);
#pragma unroll
    for (int i = 0; i < 5; ++i) {
      int idx = lane + 64 * i;
      if (idx < 288) {
        int hh = idx / 144;
        int rem = idx - hh * 144;
        int t = rem / 6;
        int s4g = rem - t * 6;
        uint2 pr = *(const uint2*)(arena + hh * 1152 + t * 48 + s4g * 8);
        float iv0 = *(const float*)(arena + 2304 + hh * 96 + t * 4);
        float4 o;
        o.x = __uint_as_float((pr.x & 0xFFFFu) << 16) * iv0;
        o.y = __uint_as_float(pr.x & 0xFFFF0000u) * iv0;
        o.z = __uint_as_float((pr.y & 0xFFFFu) << 16) * iv0;
        o.w = __uint_as_float(pr.y & 0xFFFF0000u) * iv0;
        *(float4*)(attn + abase + (size_t)(wv * 2 + hh) * 576 + t * 24 + s4g * 4) = o;
      }
    }
    // outh (separate region @18432)
#pragma unroll
    for (int hh = 0; hh < 2; ++hh) {
      int h = wv * 2 + hh;
#pragma unroll
      for (int mt = 0; mt < 2; ++mt)
#pragma unroll
        for (int r = 0; r < 4; ++r) {
          int t = mt * 16 + g * 4 + r;
          if (t < 24)
            *(unsigned short*)(smem + 18432 + swz256((unsigned)(t * 256 + (h * 16 + c) * 2))) =
                f2bs(pv[hh][mt][r]);
        }
    }
  }

  // prefetch W B-frags (hide L2 latency under barrier)
  bf16x8 Bw[4];
#pragma unroll
  for (int ks = 0; ks < 4; ++ks)
    Bw[ks] = *(const bf16x8*)(Wt + (size_t)((wv * 4 + ks) * 64 + lane) * 8);
  __syncthreads();  // (3) outh complete

  // ---- P3: out projection ----
  {
    f32x4 acc2[2] = {zf, zf};
#pragma unroll
    for (int ks = 0; ks < 4; ++ks) {
      bf16x8 Af[2];
#pragma unroll
      for (int mt = 0; mt < 2; ++mt) {
        int row = mt * 16 + c; row = row < 24 ? row : 23;
        Af[mt] = *(const bf16x8*)(smem + 18432 + swz256((unsigned)(row * 256 + ks * 64 + g * 16)));
      }
      __builtin_amdgcn_s_setprio(1);
#pragma unroll
      for (int mt = 0; mt < 2; ++mt)
        acc2[mt] = __builtin_amdgcn_mfma_f32_16x16x32_bf16(Af[mt], Bw[ks], acc2[mt], 0, 0, 0);
      __builtin_amdgcn_s_setprio(0);
    }
    int j = wv * 16 + c;
    float bj = bias[j];
    const size_t obase = (size_t)(b * Nn + n) * (Tt * Dm);
#pragma unroll
    for (int mt = 0; mt < 2; ++mt)
#pragma unroll
      for (int r = 0; r < 4; ++r) {
        int t = mt * 16 + g * 4 + r;
        if (t < 24) out[obase + (size_t)t * Dm + j] = fmaxf(acc2[mt][r] + bj, 0.f);
      }
  }
}

extern "C" void kernel_launch(void* const* d_in, const int* in_sizes, int n_in,
                              void* d_out, int out_size, void* d_ws, size_t ws_size,
                              hipStream_t stream) {
  const float* query = (const float*)d_in[0];
  const float* key   = (const float*)d_in[1];
  const float* value = (const float*)d_in[2];
  const float* qp1 = (const float*)d_in[4];
  const float* qp2 = (const float*)d_in[5];
  const float* kp1 = (const float*)d_in[6];
  const float* kp2 = (const float*)d_in[7];
  const float* vp1 = (const float*)d_in[8];
  const float* vp2 = (const float*)d_in[9];
  const float* out_W = (const float*)d_in[10];
  const float* out_b = (const float*)d_in[11];

  unsigned short* Pt  = (unsigned short*)d_ws;        // 3*PT bf16
  unsigned short* Wtf = Pt + 3 * PT;                  // 8192 bf16

  float* out = (float*)d_out;
  float* attn = out + (size_t)NBN * Tt * Dm;

  build_P_frag3<<<dim3(Nn * 8, 3), 256, 0, stream>>>(qp1, qp2, kp1, kp2, vp1, vp2, Pt);
  build_W_frag<<<1, 256, 0, stream>>>(out_W, Wtf);
  fused_attn<<<NBN, 256, 0, stream>>>(query, key, value,
                                      Pt, Pt + PT, Pt + 2 * PT, Wtf,
                                      out_b, out, attn);
}

// Round 16
// 148.914 us; speedup vs baseline: 1.0081x; 1.0081x over previous
//
#include <hip/hip_runtime.h>
#include <hip/hip_bf16.h>

// B=32, N=207, T=24, E=128, H=8, d=16, DM=64, M=32
#define Bn 32
#define Nn 207
#define Tt 24
#define Ee 128
#define Hh 8
#define Dm 64
#define Mm 32
#define NBN (Bn * Nn)                // 6624
#define PT ((size_t)Nn * 16384)     // per-tensor Pt fragment elems

typedef __attribute__((ext_vector_type(8))) short bf16x8;
typedef __attribute__((ext_vector_type(4))) float f32x4;

// Compiler-only memory fence (zero instructions): orders may-aliasing LDS
// accesses made through different pointer types across overlay phases.
#define MEMFENCE asm volatile("" ::: "memory")

__device__ __forceinline__ unsigned swz256(unsigned a) { return a ^ (((a >> 8) & 7u) << 4); }
// hardware packed f32->bf16 (RNE)
__device__ __forceinline__ unsigned cvtpk(float lo, float hi) {
  unsigned r;
  asm("v_cvt_pk_bf16_f32 %0, %1, %2" : "=v"(r) : "v"(lo), "v"(hi));
  return r;
}
__device__ __forceinline__ unsigned short f2bs(float f) {
  return (unsigned short)cvtpk(f, f);
}

// ---------------- builders (unchanged) ----------------
__global__ __launch_bounds__(256) void build_P_frag3(
    const float* __restrict__ qp1, const float* __restrict__ qp2,
    const float* __restrict__ kp1, const float* __restrict__ kp2,
    const float* __restrict__ vp1, const float* __restrict__ vp2,
    unsigned short* __restrict__ Pt) {
  const int tau = blockIdx.y;
  const float* p1 = (tau == 0) ? qp1 : (tau == 1) ? kp1 : vp1;
  const float* p2 = (tau == 0) ? qp2 : (tau == 1) ? kp2 : vp2;
  unsigned short* dst = Pt + (size_t)tau * PT;
  const int bid = blockIdx.x;
  const int n = bid >> 3;
  const int r8 = bid & 7;
  const int ks = r8 >> 1;
  const int chunk = ((r8 & 1) << 1) + (threadIdx.x >> 7);
  const int col = threadIdx.x & 127;
  const int base_i = ks * 32 + chunk * 8;
  const float* p1r = p1 + (size_t)(n * 64 + (base_i >> 1)) * Mm;
  const float* p2a = p2 + col;
  const float* p2b = p2 + 128 + col;
  float acc[8] = {};
#pragma unroll
  for (int m = 0; m < Mm; ++m) {
    float a = p2a[m * 256], b = p2b[m * 256];
#pragma unroll
    for (int jj = 0; jj < 4; ++jj) {
      float pv = p1r[jj * Mm + m];
      acc[2 * jj]     = fmaf(pv, a, acc[2 * jj]);
      acc[2 * jj + 1] = fmaf(pv, b, acc[2 * jj + 1]);
    }
  }
  const int nt = col >> 4;
  const int lane = (chunk << 4) | (col & 15);
  union { unsigned u[4]; uint4 v; } w;
#pragma unroll
  for (int jj = 0; jj < 4; ++jj) w.u[jj] = cvtpk(acc[2 * jj], acc[2 * jj + 1]);
  *(uint4*)(dst + (size_t)(((n * 8 + nt) * 4 + ks) * 64 + lane) * 8) = w.v;
}

__global__ __launch_bounds__(256) void build_W_frag(const float* __restrict__ W,
                                                    unsigned short* __restrict__ Wt) {
  for (int idx = threadIdx.x; idx < 1024; idx += 256) {
    int lane = idx & 63, ks = (idx >> 6) & 3, nt = idx >> 8;
    union { unsigned u[4]; uint4 v; } w;
#pragma unroll
    for (int jj = 0; jj < 4; ++jj) {
      float a = W[(size_t)(ks * 32 + (lane >> 4) * 8 + 2 * jj) * 64 + nt * 16 + (lane & 15)];
      float b = W[(size_t)(ks * 32 + (lane >> 4) * 8 + 2 * jj + 1) * 64 + nt * 16 + (lane & 15)];
      w.u[jj] = cvtpk(a, b);
    }
    *(uint4*)(Wt + (size_t)idx * 8) = w.v;
  }
}

struct P8 { unsigned u[8]; };

// One block per (b,n); 4 waves; 18432 B LDS. launch_bounds(256,6): the (256,8)
// attribute (VGPR cap 64) failed correctness TWICE (R11/R15 ~5e-2) while every
// (256,6) build with fences passed -- suspect allocator pathology under the
// hard cap, NOT the overlay logic (mapping re-verified). With (256,6) and
// measured ~40-52 VGPR <= 64, the HW still reaches 8 blocks/CU via LDS.
// Arena(wv) = smem + wv*4608 (arenas exactly overlay the 3x6144 staging):
//   qs@0 [24][32] xor((row&3)<<4) (1536) | ks@1536 (1536) | inv@2304 [2][24] f32
//   vT@3072 [32][24] stride 48 (1536)
//   probs overlay @0 [2 hh][24 t][24 s] stride 48 (after qs/ks frag reads; fenced)
//   outh overlay @3072 [24 t][32 ecol] stride 64, xor(((t>>2)&3)<<4)
//     (after vT frag reads; fenced)
// Out-proj reads k-block ks from wave ks's arena (cross-wave, after bar3).
__global__ __launch_bounds__(256, 6) void fused_attn(
    const float* __restrict__ Qin, const float* __restrict__ Kin,
    const float* __restrict__ Vin,
    const unsigned short* __restrict__ Ptq, const unsigned short* __restrict__ Ptk,
    const unsigned short* __restrict__ Ptv, const unsigned short* __restrict__ Wt,
    const float* __restrict__ bias,
    float* __restrict__ out, float* __restrict__ attn) {
  __shared__ __align__(16) char smem[18432];
  const int tid = threadIdx.x;
  const int lane = tid & 63;
  const int wv = tid >> 6;
  const int c = lane & 15;
  const int g = lane >> 4;
  const f32x4 zf = {0.f, 0.f, 0.f, 0.f};
  const bf16x8 zb = {0, 0, 0, 0, 0, 0, 0, 0};

  int bx = blockIdx.x;
  bx = (bx & 7) * 828 + (bx >> 3);          // bijective XCD swizzle (6624 = 8*828)
  const int n = bx >> 5;
  const int b = bx & 31;
  const size_t xbase = (size_t)(b * Nn + n) * (Tt * Ee);

  // ---- P0: stage xq/xk/xv. Batched: issue all 9 loads, then cvt+store ----
  {
    const float* src[3] = {Qin + xbase, Kin + xbase, Vin + xbase};
    float4 xr[9];
#pragma unroll
    for (int w = 0; w < 3; ++w)
#pragma unroll
      for (int it = 0; it < 3; ++it)
        xr[w * 3 + it] = *(const float4*)(src[w] + (size_t)(tid + 256 * it) * 4);
#pragma unroll
    for (int w = 0; w < 3; ++w)
#pragma unroll
      for (int it = 0; it < 3; ++it) {
        int e4 = tid + 256 * it;            // 768 float4 = 24x128
        unsigned a = swz256((unsigned)((e4 >> 5) * 256 + (e4 & 31) * 8));
        uint2 pk;
        pk.x = cvtpk(xr[w * 3 + it].x, xr[w * 3 + it].y);
        pk.y = cvtpk(xr[w * 3 + it].z, xr[w * 3 + it].w);
        *(uint2*)(smem + w * 6144 + a) = pk;
      }
  }
  __syncthreads();  // (1) staging ready

  // ---- P1: q/k/v proj; results packed bf16 in regs (8 uints each) ----
  P8 pq, pk_, pv_;
  {
#pragma unroll
    for (int w = 0; w < 3; ++w) {
      const unsigned short* Pf = (w == 0) ? Ptq : (w == 1) ? Ptk : Ptv;
      const char* xs = smem + w * 6144;
      f32x4 acc[2][2] = {{zf, zf}, {zf, zf}};
#pragma unroll
      for (int ks = 0; ks < 4; ++ks) {
        bf16x8 Bf[2], Af[2];
#pragma unroll
        for (int ntl = 0; ntl < 2; ++ntl)
          Bf[ntl] = *(const bf16x8*)(Pf + (size_t)(((n * 8 + (wv * 2 + ntl)) * 4 + ks) * 64 + lane) * 8);
#pragma unroll
        for (int mt = 0; mt < 2; ++mt) {
          int row = mt * 16 + c; row = row < 24 ? row : 23;
          Af[mt] = *(const bf16x8*)(xs + swz256((unsigned)(row * 256 + ks * 64 + g * 16)));
        }
        __builtin_amdgcn_s_setprio(1);
#pragma unroll
        for (int mt = 0; mt < 2; ++mt)
#pragma unroll
          for (int ntl = 0; ntl < 2; ++ntl)
            acc[mt][ntl] = __builtin_amdgcn_mfma_f32_16x16x32_bf16(Af[mt], Bf[ntl], acc[mt][ntl], 0, 0, 0);
        __builtin_amdgcn_s_setprio(0);
      }
      const float ps = (w == 0) ? 0.25f : 1.0f;   // fold softmax scale into q
      P8 r;
#pragma unroll
      for (int mt = 0; mt < 2; ++mt)
#pragma unroll
        for (int ntl = 0; ntl < 2; ++ntl)
#pragma unroll
          for (int half = 0; half < 2; ++half) {
            float a = fmaxf(acc[mt][ntl][half * 2], 0.f) * ps;
            float bb = fmaxf(acc[mt][ntl][half * 2 + 1], 0.f) * ps;
            r.u[(mt * 2 + ntl) * 2 + half] = cvtpk(a, bb);
          }
      if (w == 0) pq = r; else if (w == 1) pk_ = r; else pv_ = r;
    }
  }
  __syncthreads();  // (2) all staging reads done -> arenas live

  char* arena = smem + wv * 4608;

  // ---- P2a: unpack packed projections into arena slices ----
#pragma unroll
  for (int mt = 0; mt < 2; ++mt)
#pragma unroll
    for (int ntl = 0; ntl < 2; ++ntl)
#pragma unroll
      for (int half = 0; half < 2; ++half) {
        unsigned uq = pq.u[(mt * 2 + ntl) * 2 + half];
        unsigned uk = pk_.u[(mt * 2 + ntl) * 2 + half];
        unsigned uv = pv_.u[(mt * 2 + ntl) * 2 + half];
        int row0 = mt * 16 + g * 4 + half * 2;
        // vT: rows adjacent in [e][t] layout -> single uint store (both rows)
        if (row0 < 24)
          *(unsigned*)(arena + 3072 + (ntl * 16 + c) * 48 + row0 * 2) = uv;
#pragma unroll
        for (int rr = 0; rr < 2; ++rr) {
          int row = row0 + rr;
          if (row < 24) {
            unsigned short vq = (unsigned short)(rr ? (uq >> 16) : uq);
            unsigned short vk = (unsigned short)(rr ? (uk >> 16) : uk);
            unsigned adqk = (unsigned)(row * 64) +
                            (((unsigned)(ntl * 32 + c * 2)) ^ (((unsigned)row & 3u) << 4));
            *(unsigned short*)(arena + adqk) = vq;
            *(unsigned short*)(arena + 1536 + adqk) = vk;
          }
        }
      }
  MEMFENCE;  // P2a stores (ushort/uint) ordered before P2b reads (bf16x8)

  // ---- P2b: score fragments (all reads BEFORE probs overlay writes) ----
  bf16x8 Aq[2][2], Bk[2][2];   // [hh][mt/st]; k-dim = 16, g>=2 zero
#pragma unroll
  for (int hh = 0; hh < 2; ++hh)
#pragma unroll
    for (int mt = 0; mt < 2; ++mt) {
      int row = mt * 16 + c; row = row < 24 ? row : 23;
      unsigned ad = (unsigned)(row * 64) +
                    (((unsigned)(hh * 32 + g * 16)) ^ (((unsigned)row & 3u) << 4));
      Aq[hh][mt] = zb;
      Bk[hh][mt] = zb;
      if (g < 2) {
        Aq[hh][mt] = *(const bf16x8*)(arena + ad);
        Bk[hh][mt] = *(const bf16x8*)(arena + 1536 + ad);
      }
    }
  MEMFENCE;  // P2b qs/ks reads ordered before P2c probs stores (overlay WAR)

  // ---- P2c: scores + exp; store UNNORMALIZED probs (no shuffles, no reduce) ----
#pragma unroll
  for (int hh = 0; hh < 2; ++hh) {
    f32x4 sc[2][2];
    __builtin_amdgcn_s_setprio(1);
#pragma unroll
    for (int mt = 0; mt < 2; ++mt)
#pragma unroll
      for (int st = 0; st < 2; ++st)
        sc[mt][st] = __builtin_amdgcn_mfma_f32_16x16x32_bf16(Aq[hh][mt], Bk[hh][st], zf, 0, 0, 0);
    __builtin_amdgcn_s_setprio(0);
#pragma unroll
    for (int mt = 0; mt < 2; ++mt)
#pragma unroll
      for (int r = 0; r < 4; ++r) {
        int t = mt * 16 + g * 4 + r;
        float e0 = (c <= t)      ? __expf(sc[mt][0][r]) : 0.f;   // bounded by e^9
        float e1 = (16 + c <= t) ? __expf(sc[mt][1][r]) : 0.f;
        if (t < 24) {
          unsigned u = cvtpk(e0, e1);
          *(unsigned short*)(arena + hh * 1152 + t * 48 + c * 2) = (unsigned short)u;
          if (c < 8)
            *(unsigned short*)(arena + hh * 1152 + t * 48 + (16 + c) * 2) = (unsigned short)(u >> 16);
        }
      }
  }
  MEMFENCE;  // P2c probs stores ordered before P2d reads (RAW)

  // ---- P2d: row-sum MFMA (B=ones) + PV; normalize in regs; attn; outh overlay ----
  {
    bf16x8 Ap[2][2], Bv[2];
    const short one_bf = (short)0x3F80;
    bf16x8 onesf = {one_bf, one_bf, one_bf, one_bf, one_bf, one_bf, one_bf, one_bf};
    if (g >= 3) onesf = zb;   // k = g*8+j < 24 only
#pragma unroll
    for (int hh = 0; hh < 2; ++hh) {
      Bv[hh] = zb;
      if (g < 3) Bv[hh] = *(const bf16x8*)(arena + 3072 + (hh * 16 + c) * 48 + g * 16);
#pragma unroll
      for (int mt = 0; mt < 2; ++mt) {
        int row = mt * 16 + c; row = row < 24 ? row : 23;
        Ap[hh][mt] = zb;
        if (g < 3) Ap[hh][mt] = *(const bf16x8*)(arena + hh * 1152 + row * 48 + g * 16);
      }
    }
    f32x4 pv[2][2], su[2][2];
    __builtin_amdgcn_s_setprio(1);
#pragma unroll
    for (int hh = 0; hh < 2; ++hh)
#pragma unroll
      for (int mt = 0; mt < 2; ++mt) {
        su[hh][mt] = __builtin_amdgcn_mfma_f32_16x16x32_bf16(Ap[hh][mt], onesf, zf, 0, 0, 0);
        pv[hh][mt] = __builtin_amdgcn_mfma_f32_16x16x32_bf16(Ap[hh][mt], Bv[hh], zf, 0, 0, 0);
      }
    __builtin_amdgcn_s_setprio(0);
    MEMFENCE;  // vT (Bv) + probs (Ap) LDS reads ordered before inv/outh overlay stores
    // normalize pv rows; store inv (rows t = mt*16+g*4+r) for the attn write
#pragma unroll
    for (int hh = 0; hh < 2; ++hh)
#pragma unroll
      for (int mt = 0; mt < 2; ++mt) {
        float iv[4];
#pragma unroll
        for (int r = 0; r < 4; ++r) {
          iv[r] = __builtin_amdgcn_rcpf(su[hh][mt][r]);   // sum >= 1 for valid t
          pv[hh][mt][r] *= iv[r];
        }
        if (c == 0) {
#pragma unroll
          for (int rp = 0; rp < 4; rp += 2) {
            int t0 = mt * 16 + g * 4 + rp;
            if (t0 < 24) {
              float2 st2 = {iv[rp], iv[rp + 1]};
              *(float2*)(arena + 2304 + hh * 96 + t0 * 4) = st2;
            }
          }
        }
      }
    MEMFENCE;  // inv stores ordered before attn-path reads (RAW)
    // attn global write: p_un * inv[t] (coalesced float4)
    const size_t abase = (size_t)(b * Nn + n) * (Hh * Tt * Tt);
#pragma unroll
    for (int i = 0; i < 5; ++i) {
      int idx = lane + 64 * i;
      if (idx < 288) {
        int hh = idx / 144;
        int rem = idx - hh * 144;
        int t = rem / 6;
        int s4g = rem - t * 6;
        uint2 pr = *(const uint2*)(arena + hh * 1152 + t * 48 + s4g * 8);
        float iv0 = *(const float*)(arena + 2304 + hh * 96 + t * 4);
        float4 o;
        o.x = __uint_as_float((pr.x & 0xFFFFu) << 16) * iv0;
        o.y = __uint_as_float(pr.x & 0xFFFF0000u) * iv0;
        o.z = __uint_as_float((pr.y & 0xFFFFu) << 16) * iv0;
        o.w = __uint_as_float(pr.y & 0xFFFF0000u) * iv0;
        *(float4*)(attn + abase + (size_t)(wv * 2 + hh) * 576 + t * 24 + s4g * 4) = o;
      }
    }
    MEMFENCE;  // all P2d LDS reads done before overlay writes
    // outh -> arena overlay @3072 (vT dead after fenced Bv reads above)
    // layout: [24 t][32 ecol] stride 64B, xor(((t>>2)&3)<<4)
#pragma unroll
    for (int hh = 0; hh < 2; ++hh) {
#pragma unroll
      for (int mt = 0; mt < 2; ++mt)
#pragma unroll
        for (int r = 0; r < 4; ++r) {
          int t = mt * 16 + g * 4 + r;
          if (t < 24) {
            unsigned ad = 3072u + (unsigned)(t * 64) +
                          (((unsigned)((hh * 16 + c) * 2)) ^ ((((unsigned)t >> 2) & 3u) << 4));
            *(unsigned short*)(arena + ad) = f2bs(pv[hh][mt][r]);
          }
        }
    }
  }

  // prefetch W B-frags (hide L2 latency under barrier)
  bf16x8 Bw[4];
#pragma unroll
  for (int ks = 0; ks < 4; ++ks)
    Bw[ks] = *(const bf16x8*)(Wt + (size_t)((wv * 4 + ks) * 64 + lane) * 8);
  __syncthreads();  // (3) outh complete in all arenas

  // ---- P3: out projection; A k-block ks comes from wave ks's arena ----
  {
    f32x4 acc2[2] = {zf, zf};
#pragma unroll
    for (int ks = 0; ks < 4; ++ks) {
      bf16x8 Af[2];
#pragma unroll
      for (int mt = 0; mt < 2; ++mt) {
        int row = mt * 16 + c; row = row < 24 ? row : 23;
        unsigned ad = (unsigned)(ks * 4608 + 3072 + row * 64) +
                      (((unsigned)(g * 16)) ^ ((((unsigned)row >> 2) & 3u) << 4));
        Af[mt] = *(const bf16x8*)(smem + ad);
      }
      __builtin_amdgcn_s_setprio(1);
#pragma unroll
      for (int mt = 0; mt < 2; ++mt)
        acc2[mt] = __builtin_amdgcn_mfma_f32_16x16x32_bf16(Af[mt], Bw[ks], acc2[mt], 0, 0, 0);
      __builtin_amdgcn_s_setprio(0);
    }
    int j = wv * 16 + c;
    float bj = bias[j];
    const size_t obase = (size_t)(b * Nn + n) * (Tt * Dm);
#pragma unroll
    for (int mt = 0; mt < 2; ++mt)
#pragma unroll
      for (int r = 0; r < 4; ++r) {
        int t = mt * 16 + g * 4 + r;
        if (t < 24) out[obase + (size_t)t * Dm + j] = fmaxf(acc2[mt][r] + bj, 0.f);
      }
  }
}

extern "C" void kernel_launch(void* const* d_in, const int* in_sizes, int n_in,
                              void* d_out, int out_size, void* d_ws, size_t ws_size,
                              hipStream_t stream) {
  const float* query = (const float*)d_in[0];
  const float* key   = (const float*)d_in[1];
  const float* value = (const float*)d_in[2];
  const float* qp1 = (const float*)d_in[4];
  const float* qp2 = (const float*)d_in[5];
  const float* kp1 = (const float*)d_in[6];
  const float* kp2 = (const float*)d_in[7];
  const float* vp1 = (const float*)d_in[8];
  const float* vp2 = (const float*)d_in[9];
  const float* out_W = (const float*)d_in[10];
  const float* out_b = (const float*)d_in[11];

  unsigned short* Pt  = (unsigned short*)d_ws;        // 3*PT bf16
  unsigned short* Wtf = Pt + 3 * PT;                  // 8192 bf16

  float* out = (float*)d_out;
  float* attn = out + (size_t)NBN * Tt * Dm;

  build_P_frag3<<<dim3(Nn * 8, 3), 256, 0, stream>>>(qp1, qp2, kp1, kp2, vp1, vp2, Pt);
  build_W_frag<<<1, 256, 0, stream>>>(out_W, Wtf);
  fused_attn<<<NBN, 256, 0, stream>>>(query, key, value,
                                      Pt, Pt + PT, Pt + 2 * PT, Wtf,
                                      out_b, out, attn);
}